// Round 3
// baseline (375.320 us; speedup 1.0000x reference)
//
#include <hip/hip_runtime.h>

// NGH=7, SUBQ=8, SUBD=1, POS_D=3, NEG_D=5, BORDER=16, SUBD_NEG=8. B=4,C=128,H=W=256.
#define CCH   128
#define HH    256
#define WW    256
#define BB    4
#define H1    28
#define W1    28
#define QTOT  3136
#define NPOS  29
#define NNEG  80
#define NDIS  3136
#define SCOLS 3217          // 1 + NNEG + NDIS

typedef short s8v __attribute__((ext_vector_type(8)));   // 8 bf16 (4 VGPRs)
typedef float f4v __attribute__((ext_vector_type(4)));   // MFMA accumulator

__device__ __forceinline__ unsigned short f2bf(float f) {  // RNE fp32->bf16
  unsigned int u = __float_as_uint(f);
  u += 0x7fffu + ((u >> 16) & 1u);
  return (unsigned short)(u >> 16);
}
__device__ __forceinline__ float bf2f(unsigned short h) {
  return __uint_as_float(((unsigned int)h) << 16);
}

// Offsets in exact reference enumeration order (j outer asc, i inner asc).
__constant__ int POS_I[NPOS] = {
  0, -2,-1,0,1,2, -2,-1,0,1,2, -3,-2,-1,0,1,2,3, -2,-1,0,1,2, -2,-1,0,1,2, 0};
__constant__ int POS_J[NPOS] = {
  -3, -2,-2,-2,-2,-2, -1,-1,-1,-1,-1, 0,0,0,0,0,0,0, 1,1,1,1,1, 2,2,2,2,2, 3};
__constant__ int NEG_I[NNEG] = {
  0, -3,-2,-1,0,1,2,3, -4,-3,-2,-1,0,1,2,3,4, -5,-4,-3,3,4,5, -6,-5,-4,4,5,6,
  -6,-5,5,6, -6,-5,5,6, -7,-6,-5,5,6,7, -6,-5,5,6, -6,-5,5,6, -6,-5,-4,4,5,6,
  -5,-4,-3,3,4,5, -4,-3,-2,-1,0,1,2,3,4, -3,-2,-1,0,1,2,3, 0};
__constant__ int NEG_J[NNEG] = {
  -7, -6,-6,-6,-6,-6,-6,-6, -5,-5,-5,-5,-5,-5,-5,-5,-5, -4,-4,-4,-4,-4,-4,
  -3,-3,-3,-3,-3,-3, -2,-2,-2,-2, -1,-1,-1,-1, 0,0,0,0,0,0, 1,1,1,1, 2,2,2,2,
  3,3,3,3,3,3, 4,4,4,4,4,4, 5,5,5,5,5,5,5,5,5, 6,6,6,6,6,6,6, 7};

// ---- Kernel Z: zero the whole gt plane with coalesced float4 stores ----
__global__ void zerogt_kernel(float4* __restrict__ gt4, int n4) {
  int i = blockIdx.x * blockDim.x + threadIdx.x;
  if (i < n4) gt4[i] = make_float4(0.f, 0.f, 0.f, 0.f);
}

// ---- Kernel T: feat2 (B,C,H,W) fp32 -> feat2T (B,H,W,C) bf16 ----
__global__ void transpose_kernel(const float* __restrict__ feat2,
                                 unsigned short* __restrict__ feat2T) {
  __shared__ unsigned short tile[CCH][33];
  int x0 = blockIdx.x * 32;
  int y  = blockIdx.y;
  int b  = blockIdx.z;
  int tid = threadIdx.x;
  const float* src = feat2 + ((size_t)b * CCH * HH + y) * WW;
  #pragma unroll
  for (int it = 0; it < 16; ++it) {
    int idx = it * 256 + tid;
    int c = idx >> 5, xi = idx & 31;
    tile[c][xi] = f2bf(src[(size_t)c * HH * WW + x0 + xi]);
  }
  __syncthreads();
  int xi = tid >> 3, cg = (tid & 7) * 16;
  __align__(16) unsigned short tmp[16];
  #pragma unroll
  for (int k = 0; k < 16; ++k) tmp[k] = tile[cg + k][xi];
  unsigned short* dst = feat2T + ((size_t)((b * HH + y) * WW) + x0 + xi) * CCH + cg;
  *(uint4*)dst       = *(const uint4*)tmp;
  *(uint4*)(dst + 8) = *(const uint4*)(tmp + 8);
}

// ---- Kernel A: gather F1bf (strided NCHW), F2bf (coalesced NHWC), xy2, mask ----
__global__ void gather_kernel(const float* __restrict__ feat1,
                              const unsigned short* __restrict__ feat2T,
                              const float* __restrict__ aflow,
                              unsigned short* __restrict__ F1bf,
                              unsigned short* __restrict__ F2bf,
                              int* __restrict__ X2, int* __restrict__ Y2,
                              float* __restrict__ mask_out) {
  int q = blockIdx.x, c = threadIdx.x;
  int b = q / (H1 * W1), r = q % (H1 * W1);
  int y = 16 + 8 * (r / W1);
  int x = 16 + 8 * (r % W1);
  F1bf[(size_t)q * CCH + c] = f2bf(feat1[((size_t)(b * CCH + c) * HH + y) * WW + x]);
  F2bf[(size_t)q * CCH + c] = feat2T[((size_t)((b * HH + y) * WW) + x) * CCH + c];
  if (c == 0) {
    float ax = aflow[((size_t)(b * 2 + 0) * HH + y) * WW + x];
    float ay = aflow[((size_t)(b * 2 + 1) * HH + y) * WW + x];
    int x2 = (int)(ax + 0.5f);
    int y2 = (int)(ay + 0.5f);
    X2[q] = x2; Y2[q] = y2;
    mask_out[q] = (x2 >= 0 && y2 >= 0 && x2 < WW && y2 < HH) ? 1.0f : 0.0f;
  }
}

// ---- Kernel B: pos/neg scores, wave-per-offset coalesced, argmax, qconf ----
__global__ void posneg_kernel(const unsigned short* __restrict__ feat2T,
                              const float* __restrict__ conf1,
                              const float* __restrict__ conf2,
                              const unsigned short* __restrict__ F1bf,
                              const int* __restrict__ X2, const int* __restrict__ Y2,
                              float* __restrict__ scores, float* __restrict__ gt,
                              float* __restrict__ qconf_out) {
  __shared__ float posv[NPOS];
  __shared__ float negv[NNEG];
  __shared__ float bestv;
  int q = blockIdx.x;
  int t = threadIdx.x;
  int w = t >> 6, lane = t & 63;
  int b = q / (H1 * W1), r = q % (H1 * W1);
  int y = 16 + 8 * (r / W1);
  int x = 16 + 8 * (r % W1);

  // Each lane holds channels 2*lane, 2*lane+1 of f1 in registers.
  unsigned int f1p = ((const unsigned int*)(F1bf + (size_t)q * CCH))[lane];
  float f1a = __uint_as_float(f1p << 16);
  float f1b = __uint_as_float(f1p & 0xffff0000u);
  int x2 = X2[q], y2 = Y2[q];

  for (int off = w; off < NPOS + NNEG; off += 4) {   // one offset per wave per iter
    int di = (off < NPOS) ? POS_I[off] : NEG_I[off - NPOS];
    int dj = (off < NPOS) ? POS_J[off] : NEG_J[off - NPOS];
    int xk = min(max(x2 + di, 0), WW - 1);
    int yk = min(max(y2 + dj, 0), HH - 1);
    unsigned int v = ((const unsigned int*)(feat2T +
        ((size_t)((b * HH + yk) * WW) + xk) * CCH))[lane];   // 256 B coalesced row
    float s = f1a * __uint_as_float(v << 16)
            + f1b * __uint_as_float(v & 0xffff0000u);
    #pragma unroll
    for (int o = 32; o > 0; o >>= 1) s += __shfl_xor(s, o);
    if (lane == 0) {
      if (off < NPOS) posv[off] = s;
      else            negv[off - NPOS] = s;
    }
  }
  __syncthreads();

  if (t == 0) {
    float best = posv[0]; int bi = 0;
    for (int k = 1; k < NPOS; ++k)
      if (posv[k] > best) { best = posv[k]; bi = k; }   // first-occurrence argmax
    bestv = best;
    int sx = min(max(x2 + POS_I[bi], 0), WW - 1);
    int sy = min(max(y2 + POS_J[bi], 0), HH - 1);
    float c1 = conf1[((size_t)b * HH + y) * WW + x];
    float c2 = conf2[((size_t)b * HH + sy) * WW + sx];
    qconf_out[q] = 0.5f * (c1 + c2);
    gt[(size_t)q * SCOLS] = 1.0f;          // rest of gt row zeroed by zerogt_kernel
  }
  __syncthreads();

  if (t < 1 + NNEG)                         // coalesced 324 B head write
    scores[(size_t)q * SCOLS + t] = (t == 0) ? bestv : negv[t - 1];
}

// ---- Kernel C: distractor scores via bf16 MFMA; coalesced epilogue via LDS ----
__global__ void dscore_kernel(const unsigned short* __restrict__ F1bf,
                              const unsigned short* __restrict__ F2bf,
                              const int* __restrict__ X2, const int* __restrict__ Y2,
                              float* __restrict__ scores) {
  __shared__ float tile[64][66];
  int w = threadIdx.x >> 6, lane = threadIdx.x & 63;
  int qb = blockIdx.y * 64;
  int db = blockIdx.x * 64;
  int m  = lane & 15;
  int ko = (lane >> 4) * 8;

  f4v acc[4];
  #pragma unroll
  for (int dt = 0; dt < 4; ++dt) acc[dt] = (f4v){0.f, 0.f, 0.f, 0.f};

  #pragma unroll
  for (int kk = 0; kk < 4; ++kk) {
    s8v a = *(const s8v*)(F1bf + (size_t)(qb + w * 16 + m) * CCH + kk * 32 + ko);
    #pragma unroll
    for (int dt = 0; dt < 4; ++dt) {
      s8v bfr = *(const s8v*)(F2bf + (size_t)(db + dt * 16 + m) * CCH + kk * 32 + ko);
      acc[dt] = __builtin_amdgcn_mfma_f32_16x16x32_bf16(a, bfr, acc[dt], 0, 0, 0);
    }
  }

  // Stage into LDS (C/D layout: col = lane&15, row = (lane>>4)*4 + reg).
  int rbase = (lane >> 4) * 4, col = lane & 15;
  #pragma unroll
  for (int dt = 0; dt < 4; ++dt)
    #pragma unroll
    for (int r = 0; r < 4; ++r)
      tile[w * 16 + rbase + r][dt * 16 + col] = acc[dt][r];
  __syncthreads();

  // Distractor geometry for this lane's column (invariant across rows).
  int d = db + lane;
  int dbat = d / (H1 * W1), dr = d % (H1 * W1);
  int dy = 16 + 8 * (dr / W1), dx = 16 + 8 * (dr % W1);

  #pragma unroll
  for (int i = 0; i < 16; ++i) {            // wave writes 16 full 256 B rows
    int row = w * 16 + i;
    int q = qb + row;
    int x2 = X2[q], y2 = Y2[q];
    int qbat = q / (H1 * W1);
    int ddx = dx - x2, ddy = dy - y2;
    int dis2 = ddx * ddx + ddy * ddy + (dbat != qbat ? 25 : 0);   // NEG_D^2
    float v = tile[row][lane];
    if (dis2 < 25) v = 0.f;
    scores[(size_t)q * SCOLS + 1 + NNEG + d] = v;
  }
}

extern "C" void kernel_launch(void* const* d_in, const int* in_sizes, int n_in,
                              void* d_out, int out_size, void* d_ws, size_t ws_size,
                              hipStream_t stream) {
  const float* feat1 = (const float*)d_in[0];
  const float* feat2 = (const float*)d_in[1];
  const float* conf1 = (const float*)d_in[2];
  const float* conf2 = (const float*)d_in[3];
  const float* aflow = (const float*)d_in[4];

  float* out       = (float*)d_out;
  float* scores    = out;
  float* gt        = out + (size_t)QTOT * SCOLS;
  float* mask_out  = out + 2 * (size_t)QTOT * SCOLS;
  float* qconf_out = mask_out + QTOT;

  unsigned short* feat2T = (unsigned short*)d_ws;                 // B*H*W*C bf16
  unsigned short* F1bf   = feat2T + (size_t)BB * HH * WW * CCH;
  unsigned short* F2bf   = F1bf + (size_t)QTOT * CCH;
  int* X2 = (int*)(F2bf + (size_t)QTOT * CCH);
  int* Y2 = X2 + QTOT;

  int n4 = (QTOT * SCOLS) / 4;              // 3136*3217 divisible by 4
  zerogt_kernel<<<(n4 + 255) / 256, 256, 0, stream>>>((float4*)gt, n4);
  dim3 gT(WW / 32, HH, BB);
  transpose_kernel<<<gT, 256, 0, stream>>>(feat2, feat2T);
  gather_kernel<<<QTOT, CCH, 0, stream>>>(feat1, feat2T, aflow, F1bf, F2bf, X2, Y2, mask_out);
  posneg_kernel<<<QTOT, 256, 0, stream>>>(feat2T, conf1, conf2, F1bf, X2, Y2, scores, gt, qconf_out);
  dim3 gD(NDIS / 64, QTOT / 64);
  dscore_kernel<<<gD, 256, 0, stream>>>(F1bf, F2bf, X2, Y2, scores);
}

// Round 4
// 339.664 us; speedup vs baseline: 1.1050x; 1.1050x over previous
//
#include <hip/hip_runtime.h>

// NGH=7, SUBQ=8, SUBD=1, POS_D=3, NEG_D=5, BORDER=16, SUBD_NEG=8. B=4,C=128,H=W=256.
#define CCH   128
#define HH    256
#define WW    256
#define BB    4
#define H1    28
#define W1    28
#define QTOT  3136
#define NPOS  29
#define NNEG  80
#define NDIS  3136
#define SCOLS 3217          // 1 + NNEG + NDIS

typedef short s8v __attribute__((ext_vector_type(8)));   // 8 bf16 (4 VGPRs)
typedef float f4v __attribute__((ext_vector_type(4)));   // MFMA accumulator

__device__ __forceinline__ unsigned short f2bf(float f) {  // RNE fp32->bf16
  unsigned int u = __float_as_uint(f);
  u += 0x7fffu + ((u >> 16) & 1u);
  return (unsigned short)(u >> 16);
}
__device__ __forceinline__ float bflo(unsigned int v) { return __uint_as_float(v << 16); }
__device__ __forceinline__ float bfhi(unsigned int v) { return __uint_as_float(v & 0xffff0000u); }

// Offsets in exact reference enumeration order (j outer asc, i inner asc).
__constant__ int POS_I[NPOS] = {
  0, -2,-1,0,1,2, -2,-1,0,1,2, -3,-2,-1,0,1,2,3, -2,-1,0,1,2, -2,-1,0,1,2, 0};
__constant__ int POS_J[NPOS] = {
  -3, -2,-2,-2,-2,-2, -1,-1,-1,-1,-1, 0,0,0,0,0,0,0, 1,1,1,1,1, 2,2,2,2,2, 3};
__constant__ int NEG_I[NNEG] = {
  0, -3,-2,-1,0,1,2,3, -4,-3,-2,-1,0,1,2,3,4, -5,-4,-3,3,4,5, -6,-5,-4,4,5,6,
  -6,-5,5,6, -6,-5,5,6, -7,-6,-5,5,6,7, -6,-5,5,6, -6,-5,5,6, -6,-5,-4,4,5,6,
  -5,-4,-3,3,4,5, -4,-3,-2,-1,0,1,2,3,4, -3,-2,-1,0,1,2,3, 0};
__constant__ int NEG_J[NNEG] = {
  -7, -6,-6,-6,-6,-6,-6,-6, -5,-5,-5,-5,-5,-5,-5,-5,-5, -4,-4,-4,-4,-4,-4,
  -3,-3,-3,-3,-3,-3, -2,-2,-2,-2, -1,-1,-1,-1, 0,0,0,0,0,0, 1,1,1,1, 2,2,2,2,
  3,3,3,3,3,3, 4,4,4,4,4,4, 5,5,5,5,5,5,5,5,5, 6,6,6,6,6,6,6, 7};

// ---- Kernel T: feat2 (B,C,H,W) fp32 -> feat2T (B,H,W,C) bf16; fused F2bf gather ----
__global__ void transpose_kernel(const float* __restrict__ feat2,
                                 unsigned short* __restrict__ feat2T,
                                 unsigned short* __restrict__ F2bf) {
  __shared__ unsigned short tile[CCH][33];
  int x0 = blockIdx.x * 32;
  int y  = blockIdx.y;
  int b  = blockIdx.z;
  int tid = threadIdx.x;
  const float* src = feat2 + ((size_t)b * CCH * HH + y) * WW;
  #pragma unroll
  for (int it = 0; it < 16; ++it) {
    int idx = it * 256 + tid;
    int c = idx >> 5, xi = idx & 31;
    tile[c][xi] = f2bf(src[(size_t)c * HH * WW + x0 + xi]);
  }
  __syncthreads();
  int xi = tid >> 3, cg = (tid & 7) * 16;
  __align__(16) unsigned short tmp[16];
  #pragma unroll
  for (int k = 0; k < 16; ++k) tmp[k] = tile[cg + k][xi];
  unsigned short* dst = feat2T + ((size_t)((b * HH + y) * WW) + x0 + xi) * CCH + cg;
  *(uint4*)dst       = *(const uint4*)tmp;
  *(uint4*)(dst + 8) = *(const uint4*)(tmp + 8);

  // Fused: if (y, x) is a query-grid point, emit its F2bf row (for dscore).
  if ((y & 7) == 0 && y >= 16 && y <= 232) {
    int xs = x0 + (tid >> 6) * 8;            // 4 grid-x candidates per 32-wide block
    if (xs >= 16 && xs <= 232) {
      int cp = tid & 63;                     // channel pair
      int xi2 = xs - x0;
      unsigned int lo = tile[2 * cp][xi2], hi = tile[2 * cp + 1][xi2];
      int q = b * H1 * W1 + ((y - 16) >> 3) * W1 + ((xs - 16) >> 3);
      ((unsigned int*)(F2bf + (size_t)q * CCH))[cp] = lo | (hi << 16);
    }
  }
}

// ---- Kernel B: fused gather + pos/neg scores + argmax + qconf + heads ----
__global__ void posneg_kernel(const float* __restrict__ feat1,
                              const unsigned short* __restrict__ feat2T,
                              const float* __restrict__ conf1,
                              const float* __restrict__ conf2,
                              const float* __restrict__ aflow,
                              unsigned short* __restrict__ F1bf,
                              int* __restrict__ X2, int* __restrict__ Y2,
                              float* __restrict__ mask_out,
                              float* __restrict__ scores, float* __restrict__ gt,
                              float* __restrict__ qconf_out) {
  __shared__ float f1s[CCH];
  __shared__ float posv[NPOS];
  __shared__ float negv[NNEG];
  __shared__ float bestv;
  __shared__ int sxy[2];
  int q = blockIdx.x, t = threadIdx.x;
  int b = q / (H1 * W1), r = q % (H1 * W1);
  int y = 16 + 8 * (r / W1);
  int x = 16 + 8 * (r % W1);

  if (t < CCH) {                         // gather f1 (fp32 in LDS, bf16 to global)
    float v = feat1[((size_t)(b * CCH + t) * HH + y) * WW + x];
    f1s[t] = v;
    F1bf[(size_t)q * CCH + t] = f2bf(v);
  }
  if (t == 128) {
    float ax = aflow[((size_t)(b * 2 + 0) * HH + y) * WW + x];
    float ay = aflow[((size_t)(b * 2 + 1) * HH + y) * WW + x];
    int x2 = (int)(ax + 0.5f);
    int y2 = (int)(ay + 0.5f);
    X2[q] = x2; Y2[q] = y2; sxy[0] = x2; sxy[1] = y2;
    mask_out[q] = (x2 >= 0 && y2 >= 0 && x2 < WW && y2 < HH) ? 1.0f : 0.0f;
  }
  __syncthreads();
  int x2 = sxy[0], y2 = sxy[1];

  if (t < 2 * (NPOS + NNEG)) {           // 218 threads: 2 per offset, 64 ch each
    int off = t >> 1, half = t & 1;
    int di = (off < NPOS) ? POS_I[off] : NEG_I[off - NPOS];
    int dj = (off < NPOS) ? POS_J[off] : NEG_J[off - NPOS];
    int xk = min(max(x2 + di, 0), WW - 1);
    int yk = min(max(y2 + dj, 0), HH - 1);
    const uint4* p4 = (const uint4*)(feat2T +
        ((size_t)((b * HH + yk) * WW) + xk) * CCH + half * 64);
    float acc = 0.f;
    #pragma unroll
    for (int i = 0; i < 8; ++i) {        // 8 x 16 B contiguous bf16
      uint4 v = p4[i];
      float4 fa = *(const float4*)&f1s[half * 64 + i * 8];
      float4 fb = *(const float4*)&f1s[half * 64 + i * 8 + 4];
      acc += fa.x * bflo(v.x) + fa.y * bfhi(v.x)
           + fa.z * bflo(v.y) + fa.w * bfhi(v.y)
           + fb.x * bflo(v.z) + fb.y * bfhi(v.z)
           + fb.z * bflo(v.w) + fb.w * bfhi(v.w);
    }
    acc += __shfl_xor(acc, 1);           // combine halves (adjacent lanes)
    if (half == 0) {
      if (off < NPOS) posv[off] = acc;
      else            negv[off - NPOS] = acc;
    }
  }
  if (t < 1 + NNEG)
    gt[(size_t)q * SCOLS + t] = (t == 0) ? 1.0f : 0.0f;
  __syncthreads();

  if (t == 0) {
    float best = posv[0]; int bi = 0;
    for (int k = 1; k < NPOS; ++k)
      if (posv[k] > best) { best = posv[k]; bi = k; }   // first-occurrence argmax
    bestv = best;
    int sx = min(max(x2 + POS_I[bi], 0), WW - 1);
    int sy = min(max(y2 + POS_J[bi], 0), HH - 1);
    float c1 = conf1[((size_t)b * HH + y) * WW + x];
    float c2 = conf2[((size_t)b * HH + sy) * WW + sx];
    qconf_out[q] = 0.5f * (c1 + c2);
  }
  __syncthreads();

  if (t < 1 + NNEG)                      // coalesced 324 B head write
    scores[(size_t)q * SCOLS + t] = (t == 0) ? bestv : negv[t - 1];
}

// ---- Kernel C: distractor bf16 MFMA; LDS-bounce epilogue, scores+gt coalesced ----
__global__ void dscore_kernel(const unsigned short* __restrict__ F1bf,
                              const unsigned short* __restrict__ F2bf,
                              const int* __restrict__ X2, const int* __restrict__ Y2,
                              float* __restrict__ scores, float* __restrict__ gt) {
  __shared__ float tile[64][66];
  __shared__ int sx2[64], sy2[64];
  int w = threadIdx.x >> 6, lane = threadIdx.x & 63;
  int qb = blockIdx.y * 64;
  int db = blockIdx.x * 64;
  int m  = lane & 15;
  int ko = (lane >> 4) * 8;

  if (threadIdx.x < 64) {
    sx2[threadIdx.x] = X2[qb + threadIdx.x];
    sy2[threadIdx.x] = Y2[qb + threadIdx.x];
  }

  f4v acc[4];
  #pragma unroll
  for (int dt = 0; dt < 4; ++dt) acc[dt] = (f4v){0.f, 0.f, 0.f, 0.f};

  #pragma unroll
  for (int kk = 0; kk < 4; ++kk) {
    s8v a = *(const s8v*)(F1bf + (size_t)(qb + w * 16 + m) * CCH + kk * 32 + ko);
    #pragma unroll
    for (int dt = 0; dt < 4; ++dt) {
      s8v bfr = *(const s8v*)(F2bf + (size_t)(db + dt * 16 + m) * CCH + kk * 32 + ko);
      acc[dt] = __builtin_amdgcn_mfma_f32_16x16x32_bf16(a, bfr, acc[dt], 0, 0, 0);
    }
  }

  // Stage to LDS (C/D layout: col = lane&15, row = (lane>>4)*4 + reg).
  int rbase = (lane >> 4) * 4, col = lane & 15;
  #pragma unroll
  for (int dt = 0; dt < 4; ++dt)
    #pragma unroll
    for (int r = 0; r < 4; ++r)
      tile[w * 16 + rbase + r][dt * 16 + col] = acc[dt][r];
  __syncthreads();

  // Lane's distractor geometry (column-invariant across rows).
  int d = db + lane;
  int dbat = d / (H1 * W1), dr = d % (H1 * W1);
  int dy = 16 + 8 * (dr / W1), dx = 16 + 8 * (dr % W1);

  #pragma unroll
  for (int i = 0; i < 16; ++i) {         // wave writes 16 full 256 B row-runs (x2)
    int row = w * 16 + i;
    int q = qb + row;
    int qbat = q / (H1 * W1);
    int ddx = dx - sx2[row], ddy = dy - sy2[row];
    int dis2 = ddx * ddx + ddy * ddy + (dbat != qbat ? 25 : 0);   // NEG_D^2
    float v = tile[row][lane];
    if (dis2 < 25) v = 0.f;
    size_t o = (size_t)q * SCOLS + 1 + NNEG + d;
    scores[o] = v;
    gt[o] = 0.f;
  }
}

extern "C" void kernel_launch(void* const* d_in, const int* in_sizes, int n_in,
                              void* d_out, int out_size, void* d_ws, size_t ws_size,
                              hipStream_t stream) {
  const float* feat1 = (const float*)d_in[0];
  const float* feat2 = (const float*)d_in[1];
  const float* conf1 = (const float*)d_in[2];
  const float* conf2 = (const float*)d_in[3];
  const float* aflow = (const float*)d_in[4];

  float* out       = (float*)d_out;
  float* scores    = out;
  float* gt        = out + (size_t)QTOT * SCOLS;
  float* mask_out  = out + 2 * (size_t)QTOT * SCOLS;
  float* qconf_out = mask_out + QTOT;

  unsigned short* feat2T = (unsigned short*)d_ws;                 // B*H*W*C bf16
  unsigned short* F1bf   = feat2T + (size_t)BB * HH * WW * CCH;
  unsigned short* F2bf   = F1bf + (size_t)QTOT * CCH;
  int* X2 = (int*)(F2bf + (size_t)QTOT * CCH);
  int* Y2 = X2 + QTOT;

  dim3 gT(WW / 32, HH, BB);
  transpose_kernel<<<gT, 256, 0, stream>>>(feat2, feat2T, F2bf);
  posneg_kernel<<<QTOT, 256, 0, stream>>>(feat1, feat2T, conf1, conf2, aflow,
                                          F1bf, X2, Y2, mask_out, scores, gt, qconf_out);
  dim3 gD(NDIS / 64, QTOT / 64);
  dscore_kernel<<<gD, 256, 0, stream>>>(F1bf, F2bf, X2, Y2, scores, gt);
}

// Round 5
// 339.519 us; speedup vs baseline: 1.1054x; 1.0004x over previous
//
#include <hip/hip_runtime.h>

// NGH=7, SUBQ=8, SUBD=1, POS_D=3, NEG_D=5, BORDER=16, SUBD_NEG=8. B=4,C=128,H=W=256.
#define CCH   128
#define HH    256
#define WW    256
#define BB    4
#define H1    28
#define W1    28
#define QTOT  3136
#define NPOS  29
#define NNEG  80
#define NDIS  3136
#define DT64  (NDIS / 64)   // 49 distractor tiles
#define QT64  (QTOT / 64)   // 49 query tiles
#define SCOLS 3217          // 1 + NNEG + NDIS

typedef short s8v __attribute__((ext_vector_type(8)));   // 8 bf16 (4 VGPRs)
typedef float f4v __attribute__((ext_vector_type(4)));   // MFMA accumulator

__device__ __forceinline__ unsigned short f2bf(float f) {  // RNE fp32->bf16
  unsigned int u = __float_as_uint(f);
  u += 0x7fffu + ((u >> 16) & 1u);
  return (unsigned short)(u >> 16);
}
__device__ __forceinline__ float bflo(unsigned int v) { return __uint_as_float(v << 16); }
__device__ __forceinline__ float bfhi(unsigned int v) { return __uint_as_float(v & 0xffff0000u); }

// Offsets in exact reference enumeration order (j outer asc, i inner asc).
__constant__ int POS_I[NPOS] = {
  0, -2,-1,0,1,2, -2,-1,0,1,2, -3,-2,-1,0,1,2,3, -2,-1,0,1,2, -2,-1,0,1,2, 0};
__constant__ int POS_J[NPOS] = {
  -3, -2,-2,-2,-2,-2, -1,-1,-1,-1,-1, 0,0,0,0,0,0,0, 1,1,1,1,1, 2,2,2,2,2, 3};
__constant__ int NEG_I[NNEG] = {
  0, -3,-2,-1,0,1,2,3, -4,-3,-2,-1,0,1,2,3,4, -5,-4,-3,3,4,5, -6,-5,-4,4,5,6,
  -6,-5,5,6, -6,-5,5,6, -7,-6,-5,5,6,7, -6,-5,5,6, -6,-5,5,6, -6,-5,-4,4,5,6,
  -5,-4,-3,3,4,5, -4,-3,-2,-1,0,1,2,3,4, -3,-2,-1,0,1,2,3, 0};
__constant__ int NEG_J[NNEG] = {
  -7, -6,-6,-6,-6,-6,-6,-6, -5,-5,-5,-5,-5,-5,-5,-5,-5, -4,-4,-4,-4,-4,-4,
  -3,-3,-3,-3,-3,-3, -2,-2,-2,-2, -1,-1,-1,-1, 0,0,0,0,0,0, 1,1,1,1, 2,2,2,2,
  3,3,3,3,3,3, 4,4,4,4,4,4, 5,5,5,5,5,5,5,5,5, 6,6,6,6,6,6,6, 7};

// ---- Kernel T: feat2 NCHW fp32 -> NHWC bf16, fused F1bf/F2bf/xy2/mask staging ----
__global__ void transpose_kernel(const float* __restrict__ feat2,
                                 const float* __restrict__ feat1,
                                 const float* __restrict__ aflow,
                                 unsigned short* __restrict__ feat2T,
                                 unsigned short* __restrict__ F1bf,
                                 unsigned short* __restrict__ F2bf,
                                 int* __restrict__ X2, int* __restrict__ Y2,
                                 float* __restrict__ mask_out) {
  __shared__ unsigned short tile[CCH][33];
  int x0 = blockIdx.x * 32;
  int y  = blockIdx.y;
  int b  = blockIdx.z;
  int tid = threadIdx.x;
  const float* src = feat2 + ((size_t)b * CCH * HH + y) * WW;
  #pragma unroll
  for (int it = 0; it < 4; ++it) {         // float4 reads: 4x fewer VMEM insts
    int idx = it * 256 + tid;              // 0..1023 = 128 c-rows x 8 quads
    int c = idx >> 3, xq = idx & 7;
    float4 v = ((const float4*)(src + (size_t)c * HH * WW + x0))[xq];
    int xb = xq * 4;
    tile[c][xb + 0] = f2bf(v.x);
    tile[c][xb + 1] = f2bf(v.y);
    tile[c][xb + 2] = f2bf(v.z);
    tile[c][xb + 3] = f2bf(v.w);
  }
  __syncthreads();
  int xi = tid >> 3, cg = (tid & 7) * 16;
  __align__(16) unsigned short tmp[16];
  #pragma unroll
  for (int k = 0; k < 16; ++k) tmp[k] = tile[cg + k][xi];
  unsigned short* dst = feat2T + ((size_t)((b * HH + y) * WW) + x0 + xi) * CCH + cg;
  *(uint4*)dst       = *(const uint4*)tmp;
  *(uint4*)(dst + 8) = *(const uint4*)(tmp + 8);

  // Grid-point staging: F2bf from LDS tile, F1bf from feat1, xy2/mask from aflow.
  if ((y & 7) == 0 && y >= 16 && y <= 232) {
    int xs = x0 + (tid >> 6) * 8;          // 4 grid-x candidates per block
    if (xs >= 16 && xs <= 232) {
      int cp = tid & 63;                   // channel pair
      int q = b * H1 * W1 + ((y - 16) >> 3) * W1 + ((xs - 16) >> 3);
      int xi2 = xs - x0;
      unsigned int lo = tile[2 * cp][xi2], hi = tile[2 * cp + 1][xi2];
      ((unsigned int*)(F2bf + (size_t)q * CCH))[cp] = lo | (hi << 16);
      const float* f1p = feat1 + ((size_t)(b * CCH + 2 * cp) * HH + y) * WW + xs;
      unsigned int l1 = f2bf(f1p[0]);
      unsigned int h1 = f2bf(f1p[(size_t)HH * WW]);
      ((unsigned int*)(F1bf + (size_t)q * CCH))[cp] = l1 | (h1 << 16);
      if (cp == 0) {
        float ax = aflow[((size_t)(b * 2 + 0) * HH + y) * WW + xs];
        float ay = aflow[((size_t)(b * 2 + 1) * HH + y) * WW + xs];
        int x2 = (int)(ax + 0.5f);
        int y2 = (int)(ay + 0.5f);
        X2[q] = x2; Y2[q] = y2;
        mask_out[q] = (x2 >= 0 && y2 >= 0 && x2 < WW && y2 < HH) ? 1.0f : 0.0f;
      }
    }
  }
}

// ---- Kernel M: fused posneg (blocks 0..QTOT-1) + dscore (blocks QTOT..) ----
__global__ void main_kernel(const unsigned short* __restrict__ feat2T,
                            const float* __restrict__ conf1,
                            const float* __restrict__ conf2,
                            const unsigned short* __restrict__ F1bf,
                            const unsigned short* __restrict__ F2bf,
                            const int* __restrict__ X2, const int* __restrict__ Y2,
                            float* __restrict__ scores, float* __restrict__ gt,
                            float* __restrict__ qconf_out) {
  __shared__ union {
    struct { float tile[64][66]; int sx2[64]; int sy2[64]; } ds;
    struct { __align__(16) float f1s[CCH]; float posv[NPOS]; float negv[NNEG];
             float bestv; } pn;
  } sm;

  if (blockIdx.x < QTOT) {
    // ---------------- posneg branch ----------------
    int q = blockIdx.x, t = threadIdx.x;
    int b = q / (H1 * W1), r = q % (H1 * W1);
    int y = 16 + 8 * (r / W1);
    int x = 16 + 8 * (r % W1);

    if (t < 64) {                          // coalesced 256 B f1 row -> LDS fp32
      unsigned int u = ((const unsigned int*)(F1bf + (size_t)q * CCH))[t];
      sm.pn.f1s[2 * t]     = bflo(u);
      sm.pn.f1s[2 * t + 1] = bfhi(u);
    }
    int x2 = X2[q], y2 = Y2[q];            // L2-broadcast
    __syncthreads();

    if (t < 2 * (NPOS + NNEG)) {           // 218 threads: 2 per offset, 64 ch each
      int off = t >> 1, half = t & 1;
      int di = (off < NPOS) ? POS_I[off] : NEG_I[off - NPOS];
      int dj = (off < NPOS) ? POS_J[off] : NEG_J[off - NPOS];
      int xk = min(max(x2 + di, 0), WW - 1);
      int yk = min(max(y2 + dj, 0), HH - 1);
      const uint4* p4 = (const uint4*)(feat2T +
          ((size_t)((b * HH + yk) * WW) + xk) * CCH + half * 64);
      float acc = 0.f;
      #pragma unroll
      for (int i = 0; i < 8; ++i) {        // 8 x 16 B contiguous bf16
        uint4 v = p4[i];
        float4 fa = *(const float4*)&sm.pn.f1s[half * 64 + i * 8];
        float4 fb = *(const float4*)&sm.pn.f1s[half * 64 + i * 8 + 4];
        acc += fa.x * bflo(v.x) + fa.y * bfhi(v.x)
             + fa.z * bflo(v.y) + fa.w * bfhi(v.y)
             + fb.x * bflo(v.z) + fb.y * bfhi(v.z)
             + fb.z * bflo(v.w) + fb.w * bfhi(v.w);
      }
      acc += __shfl_xor(acc, 1);           // combine halves (adjacent lanes)
      if (half == 0) {
        if (off < NPOS) sm.pn.posv[off] = acc;
        else            sm.pn.negv[off - NPOS] = acc;
      }
    }
    if (t < 1 + NNEG)
      gt[(size_t)q * SCOLS + t] = (t == 0) ? 1.0f : 0.0f;
    __syncthreads();

    if (t == 0) {
      float best = sm.pn.posv[0]; int bi = 0;
      for (int k = 1; k < NPOS; ++k)
        if (sm.pn.posv[k] > best) { best = sm.pn.posv[k]; bi = k; }  // first occurrence
      sm.pn.bestv = best;
      int sx = min(max(x2 + POS_I[bi], 0), WW - 1);
      int sy = min(max(y2 + POS_J[bi], 0), HH - 1);
      float c1 = conf1[((size_t)b * HH + y) * WW + x];
      float c2 = conf2[((size_t)b * HH + sy) * WW + sx];
      qconf_out[q] = 0.5f * (c1 + c2);
    }
    __syncthreads();

    if (t < 1 + NNEG)                      // coalesced 324 B head write
      scores[(size_t)q * SCOLS + t] = (t == 0) ? sm.pn.bestv : sm.pn.negv[t - 1];

  } else {
    // ---------------- dscore branch (bf16 MFMA 64q x 64d) ----------------
    int bid = blockIdx.x - QTOT;
    int qb = (bid / DT64) * 64;
    int db = (bid % DT64) * 64;
    int w = threadIdx.x >> 6, lane = threadIdx.x & 63;
    int m  = lane & 15;
    int ko = (lane >> 4) * 8;

    if (threadIdx.x < 64) {
      sm.ds.sx2[threadIdx.x] = X2[qb + threadIdx.x];
      sm.ds.sy2[threadIdx.x] = Y2[qb + threadIdx.x];
    }

    f4v acc[4];
    #pragma unroll
    for (int dt = 0; dt < 4; ++dt) acc[dt] = (f4v){0.f, 0.f, 0.f, 0.f};

    #pragma unroll
    for (int kk = 0; kk < 4; ++kk) {
      s8v a = *(const s8v*)(F1bf + (size_t)(qb + w * 16 + m) * CCH + kk * 32 + ko);
      #pragma unroll
      for (int dt = 0; dt < 4; ++dt) {
        s8v bfr = *(const s8v*)(F2bf + (size_t)(db + dt * 16 + m) * CCH + kk * 32 + ko);
        acc[dt] = __builtin_amdgcn_mfma_f32_16x16x32_bf16(a, bfr, acc[dt], 0, 0, 0);
      }
    }

    // Stage to LDS (C/D layout: col = lane&15, row = (lane>>4)*4 + reg).
    int rbase = (lane >> 4) * 4, col = lane & 15;
    #pragma unroll
    for (int dt = 0; dt < 4; ++dt)
      #pragma unroll
      for (int r = 0; r < 4; ++r)
        sm.ds.tile[w * 16 + rbase + r][dt * 16 + col] = acc[dt][r];
    __syncthreads();

    // Lane's distractor geometry (column-invariant across rows).
    int d = db + lane;
    int dbat = d / (H1 * W1), dr = d % (H1 * W1);
    int dy = 16 + 8 * (dr / W1), dx = 16 + 8 * (dr % W1);

    #pragma unroll
    for (int i = 0; i < 16; ++i) {         // 16 full 256 B row-runs, nontemporal
      int row = w * 16 + i;
      int q = qb + row;
      int qbat = q / (H1 * W1);
      int ddx = dx - sm.ds.sx2[row], ddy = dy - sm.ds.sy2[row];
      int dis2 = ddx * ddx + ddy * ddy + (dbat != qbat ? 25 : 0);   // NEG_D^2
      float v = sm.ds.tile[row][lane];
      if (dis2 < 25) v = 0.f;
      size_t o = (size_t)q * SCOLS + 1 + NNEG + d;
      __builtin_nontemporal_store(v,   &scores[o]);
      __builtin_nontemporal_store(0.f, &gt[o]);
    }
  }
}

extern "C" void kernel_launch(void* const* d_in, const int* in_sizes, int n_in,
                              void* d_out, int out_size, void* d_ws, size_t ws_size,
                              hipStream_t stream) {
  const float* feat1 = (const float*)d_in[0];
  const float* feat2 = (const float*)d_in[1];
  const float* conf1 = (const float*)d_in[2];
  const float* conf2 = (const float*)d_in[3];
  const float* aflow = (const float*)d_in[4];

  float* out       = (float*)d_out;
  float* scores    = out;
  float* gt        = out + (size_t)QTOT * SCOLS;
  float* mask_out  = out + 2 * (size_t)QTOT * SCOLS;
  float* qconf_out = mask_out + QTOT;

  unsigned short* feat2T = (unsigned short*)d_ws;                 // B*H*W*C bf16
  unsigned short* F1bf   = feat2T + (size_t)BB * HH * WW * CCH;
  unsigned short* F2bf   = F1bf + (size_t)QTOT * CCH;
  int* X2 = (int*)(F2bf + (size_t)QTOT * CCH);
  int* Y2 = X2 + QTOT;

  dim3 gT(WW / 32, HH, BB);
  transpose_kernel<<<gT, 256, 0, stream>>>(feat2, feat1, aflow, feat2T,
                                           F1bf, F2bf, X2, Y2, mask_out);
  main_kernel<<<QTOT + DT64 * QT64, 256, 0, stream>>>(feat2T, conf1, conf2,
                                                      F1bf, F2bf, X2, Y2,
                                                      scores, gt, qconf_out);
}